// Round 3
// baseline (322.212 us; speedup 1.0000x reference)
//
#include <hip/hip_runtime.h>
#include <math.h>

#define KK      7
#define C1      21
#define NPLANES (KK * KK * C1)   // 1029
#define H       100
#define W       100

// ---------------------------------------------------------------------------
// Kernel 0: zero the 2000x21 accumulator (d_ws is poisoned 0xAA each call).
// ---------------------------------------------------------------------------
__global__ __launch_bounds__(256) void zero_acc(float* __restrict__ acc, int n)
{
    int i = blockIdx.x * 256 + threadIdx.x;
    if (i < n) acc[i] = 0.f;
}

// ---------------------------------------------------------------------------
// Kernel A (fused): one block per plane p=(j*7+l)*21+c of the LAST batch elem.
//  1. stage 100x100 plane in LDS (40 KB; 4 blocks/CU = 160 KB exact fit)
//  2. in-place 2-D inclusive integral (row scan + col scan)
//  3. all ROIs: 4 LDS lookups -> atomicAdd into acc[n*C1 + c]
// ---------------------------------------------------------------------------
__global__ __launch_bounds__(256) void plane_accum(
    const float* __restrict__ src,   // full cls_conv_out
    size_t batch_off,                // offset of last batch element (elements)
    const int*  __restrict__ rois,   // [nrois][4] = ymin,xmin,ymax,xmax
    int nrois,
    float* __restrict__ acc)         // [nrois][C1]
{
    const int p  = blockIdx.x;
    const int c  = p % C1;
    const int jl = p / C1;
    const int l  = jl % KK;
    const int j  = jl / KK;
    const int t  = threadIdx.x;

    __shared__ float tile[H * W];    // exactly 40000 B

    // 1. coalesced vectorized stage (40 KB = 2500 float4)
    {
        const float4* p4 = (const float4*)(src + batch_off + (size_t)p * (H * W));
        float4* t4 = (float4*)tile;
        for (int i = t; i < (H * W) / 4; i += 256) t4[i] = p4[i];
    }
    __syncthreads();

    // 2a. row-prefix: thread y scans row y (inclusive)
    if (t < H) {
        float s = 0.f;
        int base = t * W;
        for (int x = 0; x < W; ++x) { s += tile[base + x]; tile[base + x] = s; }
    }
    __syncthreads();

    // 2b. col-prefix: thread x scans column x (lane-consecutive -> conflict-free)
    if (t < W) {
        float s = 0.f;
        for (int y = 0; y < H; ++y) { s += tile[y * W + t]; tile[y * W + t] = s; }
    }
    __syncthreads();

    // 3. ROI lookups.  Inclusive integral I[y][x] = sum_{y'<=y, x'<=x}.
    //    rect rows [y0, y0+ys), cols [x0, x0+xs):
    //    S = I[y1][x1] - I[y0-1][x1] - I[y1][x0-1] + I[y0-1][x0-1]
    for (int n = t; n < nrois; n += 256) {
        const int4 r  = ((const int4*)rois)[n];   // ymin,xmin,ymax,xmax
        const int ys  = (r.z - r.x) / KK;
        const int xs  = (r.w - r.y) / KK;
        const int y0  = r.x + j * ys;
        const int x0  = r.y + l * xs;
        const int y1  = y0 + ys - 1;              // <= 94 < 100
        const int x1  = x0 + xs - 1;

        float S = tile[y1 * W + x1];
        if (x0 > 0)           S -= tile[y1 * W + (x0 - 1)];
        if (y0 > 0)           S -= tile[(y0 - 1) * W + x1];
        if (y0 > 0 && x0 > 0) S += tile[(y0 - 1) * W + (x0 - 1)];

        atomicAdd(&acc[(size_t)n * C1 + c], S);
    }
}

// ---------------------------------------------------------------------------
// Kernel B: one thread per ROI -> scale by 1/(49*ys*xs), softmax over 21.
// ---------------------------------------------------------------------------
__global__ __launch_bounds__(256) void softmax_out(
    const float* __restrict__ acc,
    const int*   __restrict__ rois,
    int nrois,
    float*       __restrict__ out)
{
    const int n = blockIdx.x * 256 + threadIdx.x;
    if (n >= nrois) return;

    const int4 r  = ((const int4*)rois)[n];
    const int ys  = (r.z - r.x) / KK;
    const int xs  = (r.w - r.y) / KK;
    const float inv = 1.0f / (49.0f * (float)(ys * xs));

    float v[C1];
    float m = -INFINITY;
    #pragma unroll
    for (int c = 0; c < C1; ++c) {
        v[c] = acc[(size_t)n * C1 + c] * inv;
        m = fmaxf(m, v[c]);
    }
    float s = 0.f;
    #pragma unroll
    for (int c = 0; c < C1; ++c) { v[c] = __expf(v[c] - m); s += v[c]; }
    const float rs = 1.0f / s;
    #pragma unroll
    for (int c = 0; c < C1; ++c) out[(size_t)n * C1 + c] = v[c] * rs;
}

// ---------------------------------------------------------------------------
// Fallback (ws too small for 168 KB accumulator): direct rectangle summation.
// ---------------------------------------------------------------------------
__global__ __launch_bounds__(256) void roi_pool_direct(
    const float* __restrict__ src,
    size_t batch_off,
    const int*   __restrict__ rois,
    float*       __restrict__ out)
{
    const int n = blockIdx.x;
    const int t = threadIdx.x;

    __shared__ float chsum[C1];
    if (t < C1) chsum[t] = 0.f;
    __syncthreads();

    const int ymin = rois[4 * n + 0];
    const int xmin = rois[4 * n + 1];
    const int ymax = rois[4 * n + 2];
    const int xmax = rois[4 * n + 3];
    const int ys = (ymax - ymin) / KK;
    const int xs = (xmax - xmin) / KK;

    const float* base = src + batch_off;

    for (int idx = t; idx < NPLANES; idx += blockDim.x) {
        const int c  = idx % C1;
        const int jl = idx / C1;
        const int l  = jl % KK;
        const int j  = jl / KK;
        const int y0 = ymin + j * ys;
        const int x0 = xmin + l * xs;
        const float* plane = base + (size_t)idx * (H * W);
        float s = 0.f;
        for (int y = y0; y < y0 + ys; ++y) {
            const float* row = plane + (size_t)y * W + x0;
            for (int x = 0; x < xs; ++x) s += row[x];
        }
        atomicAdd(&chsum[c], s);
    }
    __syncthreads();

    if (t == 0) {
        const float inv = 1.0f / (49.0f * (float)(ys * xs));
        float m = -INFINITY;
        float v[C1];
        for (int c = 0; c < C1; ++c) { v[c] = chsum[c] * inv; m = fmaxf(m, v[c]); }
        float s = 0.f;
        for (int c = 0; c < C1; ++c) { v[c] = expf(v[c] - m); s += v[c]; }
        const float rs = 1.0f / s;
        for (int c = 0; c < C1; ++c) out[(size_t)n * C1 + c] = v[c] * rs;
    }
}

extern "C" void kernel_launch(void* const* d_in, const int* in_sizes, int n_in,
                              void* d_out, int out_size, void* d_ws, size_t ws_size,
                              hipStream_t stream)
{
    const float* cls  = (const float*)d_in[0];
    const int*   rois = (const int*)d_in[1];
    float*       out  = (float*)d_out;

    const int nrois = in_sizes[1] / 4;                         // 2000
    const size_t plane_elems = (size_t)NPLANES * H * W;        // 10.29 M
    const int B = (int)((size_t)in_sizes[0] / plane_elems);    // 4
    const size_t batch_off = (size_t)(B - 1) * plane_elems;

    const int acc_n = nrois * C1;                              // 42000
    const size_t need = (size_t)acc_n * sizeof(float);         // 168 KB
    if (ws_size >= need) {
        float* acc = (float*)d_ws;
        zero_acc<<<(acc_n + 255) / 256, 256, 0, stream>>>(acc, acc_n);
        plane_accum<<<NPLANES, 256, 0, stream>>>(cls, batch_off, rois, nrois, acc);
        softmax_out<<<(nrois + 255) / 256, 256, 0, stream>>>(acc, rois, nrois, out);
    } else {
        roi_pool_direct<<<nrois, 256, 0, stream>>>(cls, batch_off, rois, out);
    }
}

// Round 4
// 223.375 us; speedup vs baseline: 1.4425x; 1.4425x over previous
//
#include <hip/hip_runtime.h>
#include <math.h>

#define KK      7
#define C1      21
#define NPLANES (KK * KK * C1)   // 1029
#define H       100
#define W       100

// ---------------------------------------------------------------------------
// Stage 1: one block per plane p = (j*7+l)*21 + c of the LAST batch element.
//  1. stage 100x100 plane in LDS (40 KB; 4 blocks/CU = 160 KB exact fit)
//  2. in-place 2-D inclusive integral (row scan + col scan)
//  3. all ROIs: 4 LDS lookups -> partial[p][n]  (plane-major, coalesced store)
// NO atomics anywhere.
// ---------------------------------------------------------------------------
__global__ __launch_bounds__(256) void plane_partial(
    const float* __restrict__ src,   // full cls_conv_out
    size_t batch_off,                // offset of last batch element (elements)
    const int*  __restrict__ rois,   // [nrois][4] = ymin,xmin,ymax,xmax
    int nrois,
    float* __restrict__ partial)     // [NPLANES][nrois]
{
    const int p  = blockIdx.x;
    const int jl = p / C1;
    const int l  = jl % KK;
    const int j  = jl / KK;
    const int t  = threadIdx.x;

    __shared__ float tile[H * W];    // exactly 40000 B

    // 1. coalesced vectorized stage (40 KB = 2500 float4)
    {
        const float4* p4 = (const float4*)(src + batch_off + (size_t)p * (H * W));
        float4* t4 = (float4*)tile;
        for (int i = t; i < (H * W) / 4; i += 256) t4[i] = p4[i];
    }
    __syncthreads();

    // 2a. row-prefix: thread y scans row y (inclusive).
    //     (8-way bank conflict here costs ~600 cyc/block total — accepted.)
    if (t < H) {
        float s = 0.f;
        int base = t * W;
        for (int x = 0; x < W; ++x) { s += tile[base + x]; tile[base + x] = s; }
    }
    __syncthreads();

    // 2b. col-prefix: thread x scans column x (lane-consecutive, conflict-free)
    if (t < W) {
        float s = 0.f;
        for (int y = 0; y < H; ++y) { s += tile[y * W + t]; tile[y * W + t] = s; }
    }
    __syncthreads();

    // 3. ROI lookups.  Inclusive integral I[y][x] = sum_{y'<=y, x'<=x}.
    //    rect rows [y0, y0+ys), cols [x0, x0+xs):
    //    S = I[y1][x1] - I[y0-1][x1] - I[y1][x0-1] + I[y0-1][x0-1]
    float* prow = partial + (size_t)p * nrois;
    for (int n = t; n < nrois; n += 256) {
        const int4 r  = ((const int4*)rois)[n];   // ymin,xmin,ymax,xmax
        const int ys  = (r.z - r.x) / KK;
        const int xs  = (r.w - r.y) / KK;
        const int y0  = r.x + j * ys;
        const int x0  = r.y + l * xs;
        const int y1  = y0 + ys - 1;              // <= 94 < 100
        const int x1  = x0 + xs - 1;

        float S = tile[y1 * W + x1];
        if (x0 > 0)           S -= tile[y1 * W + (x0 - 1)];
        if (y0 > 0)           S -= tile[(y0 - 1) * W + x1];
        if (y0 > 0 && x0 > 0) S += tile[(y0 - 1) * W + (x0 - 1)];

        prow[n] = S;                              // coalesced 4B store
    }
}

// ---------------------------------------------------------------------------
// Stage 2: channel sums.  Block (bn, c): thread owns ROI n, sums 49 (j,l)
// contributions for channel c.  Every load is lane-coalesced (stride over n).
// ---------------------------------------------------------------------------
__global__ __launch_bounds__(256) void reduce_chan(
    const float* __restrict__ partial,   // [NPLANES][nrois]
    int nrois,
    float* __restrict__ chansum)         // [nrois][C1]
{
    const int c = blockIdx.y;
    const int n = blockIdx.x * 256 + threadIdx.x;
    if (n >= nrois) return;

    float s = 0.f;
    for (int jl = 0; jl < KK * KK; ++jl) {
        s += partial[(size_t)(jl * C1 + c) * nrois + n];
    }
    chansum[(size_t)n * C1 + c] = s;
}

// ---------------------------------------------------------------------------
// Stage 3: one thread per ROI -> scale by 1/(49*ys*xs), softmax over 21.
// ---------------------------------------------------------------------------
__global__ __launch_bounds__(256) void softmax_out(
    const float* __restrict__ chansum,
    const int*   __restrict__ rois,
    int nrois,
    float*       __restrict__ out)
{
    const int n = blockIdx.x * 256 + threadIdx.x;
    if (n >= nrois) return;

    const int4 r  = ((const int4*)rois)[n];
    const int ys  = (r.z - r.x) / KK;
    const int xs  = (r.w - r.y) / KK;
    const float inv = 1.0f / (49.0f * (float)(ys * xs));

    float v[C1];
    float m = -INFINITY;
    #pragma unroll
    for (int c = 0; c < C1; ++c) {
        v[c] = chansum[(size_t)n * C1 + c] * inv;
        m = fmaxf(m, v[c]);
    }
    float s = 0.f;
    #pragma unroll
    for (int c = 0; c < C1; ++c) { v[c] = __expf(v[c] - m); s += v[c]; }
    const float rs = 1.0f / s;
    #pragma unroll
    for (int c = 0; c < C1; ++c) out[(size_t)n * C1 + c] = v[c] * rs;
}

// ---------------------------------------------------------------------------
// Fallback (ws too small): direct rectangle summation from global.
// ---------------------------------------------------------------------------
__global__ __launch_bounds__(256) void roi_pool_direct(
    const float* __restrict__ src,
    size_t batch_off,
    const int*   __restrict__ rois,
    float*       __restrict__ out)
{
    const int n = blockIdx.x;
    const int t = threadIdx.x;

    __shared__ float chsum[C1];
    if (t < C1) chsum[t] = 0.f;
    __syncthreads();

    const int ymin = rois[4 * n + 0];
    const int xmin = rois[4 * n + 1];
    const int ymax = rois[4 * n + 2];
    const int xmax = rois[4 * n + 3];
    const int ys = (ymax - ymin) / KK;
    const int xs = (xmax - xmin) / KK;

    const float* base = src + batch_off;

    for (int idx = t; idx < NPLANES; idx += blockDim.x) {
        const int c  = idx % C1;
        const int jl = idx / C1;
        const int l  = jl % KK;
        const int j  = jl / KK;
        const int y0 = ymin + j * ys;
        const int x0 = xmin + l * xs;
        const float* plane = base + (size_t)idx * (H * W);
        float s = 0.f;
        for (int y = y0; y < y0 + ys; ++y) {
            const float* row = plane + (size_t)y * W + x0;
            for (int x = 0; x < xs; ++x) s += row[x];
        }
        atomicAdd(&chsum[c], s);
    }
    __syncthreads();

    if (t == 0) {
        const float inv = 1.0f / (49.0f * (float)(ys * xs));
        float m = -INFINITY;
        float v[C1];
        for (int c = 0; c < C1; ++c) { v[c] = chsum[c] * inv; m = fmaxf(m, v[c]); }
        float s = 0.f;
        for (int c = 0; c < C1; ++c) { v[c] = expf(v[c] - m); s += v[c]; }
        const float rs = 1.0f / s;
        for (int c = 0; c < C1; ++c) out[(size_t)n * C1 + c] = v[c] * rs;
    }
}

extern "C" void kernel_launch(void* const* d_in, const int* in_sizes, int n_in,
                              void* d_out, int out_size, void* d_ws, size_t ws_size,
                              hipStream_t stream)
{
    const float* cls  = (const float*)d_in[0];
    const int*   rois = (const int*)d_in[1];
    float*       out  = (float*)d_out;

    const int nrois = in_sizes[1] / 4;                         // 2000
    const size_t plane_elems = (size_t)NPLANES * H * W;        // 10.29 M
    const int B = (int)((size_t)in_sizes[0] / plane_elems);    // 4
    const size_t batch_off = (size_t)(B - 1) * plane_elems;

    const size_t partial_bytes = (size_t)NPLANES * nrois * sizeof(float);  // ~8.2 MB
    const size_t chansum_off   = (partial_bytes + 255) & ~(size_t)255;
    const size_t need = chansum_off + (size_t)nrois * C1 * sizeof(float);

    if (ws_size >= need) {
        float* partial = (float*)d_ws;
        float* chansum = (float*)((char*)d_ws + chansum_off);

        plane_partial<<<NPLANES, 256, 0, stream>>>(cls, batch_off, rois, nrois, partial);

        dim3 rgrid((nrois + 255) / 256, C1);
        reduce_chan<<<rgrid, 256, 0, stream>>>(partial, nrois, chansum);

        softmax_out<<<(nrois + 255) / 256, 256, 0, stream>>>(chansum, rois, nrois, out);
    } else {
        roi_pool_direct<<<nrois, 256, 0, stream>>>(cls, batch_off, rois, out);
    }
}

// Round 5
// 218.768 us; speedup vs baseline: 1.4728x; 1.0211x over previous
//
#include <hip/hip_runtime.h>
#include <math.h>

#define KK      7
#define C1      21
#define NPLANES (KK * KK * C1)   // 1029
#define H       100
#define W       100
#define TS      101              // padded LDS row stride: bank stride 5 (coprime 32)

// ---------------------------------------------------------------------------
// Stage 1: one block per plane p = (j*7+l)*21 + c of the LAST batch element.
//  1. stage 100x100 plane in LDS at stride 101 (40.4 KB; 4 blocks/CU fits 160K)
//  2. in-place 2-D inclusive integral (row scan + col scan), conflict-free
//  3. all ROIs: 4 LDS lookups -> partial[p][n]  (plane-major, coalesced store)
// ---------------------------------------------------------------------------
__global__ __launch_bounds__(256) void plane_partial(
    const float* __restrict__ src,   // full cls_conv_out
    size_t batch_off,                // offset of last batch element (elements)
    const int*  __restrict__ rois,   // [nrois][4] = ymin,xmin,ymax,xmax
    int nrois,
    float* __restrict__ partial)     // [NPLANES][nrois]
{
    const int p  = blockIdx.x;
    const int jl = p / C1;
    const int l  = jl % KK;
    const int j  = jl / KK;
    const int t  = threadIdx.x;

    __shared__ float tile[H * TS];   // 40400 B

    // 1. stage: float4 global loads (row-aligned since 100%4==0), scalar LDS
    //    writes into the padded layout.
    {
        const float4* p4 = (const float4*)(src + batch_off + (size_t)p * (H * W));
        for (int i = t; i < (H * W) / 4; i += 256) {
            float4 v = p4[i];
            int g = i * 4;
            int y = g / W, x = g - y * W;
            float* d = &tile[y * TS + x];
            d[0] = v.x; d[1] = v.y; d[2] = v.z; d[3] = v.w;
        }
    }
    __syncthreads();

    // 2a. row-prefix: thread y scans row y.  bank(t,x) = (5t + x) & 31:
    //     distinct across 32 lanes, 2 lanes/bank across wave64 -> free.
    if (t < H) {
        float s = 0.f;
        float* row = &tile[t * TS];
        for (int x = 0; x < W; ++x) { s += row[x]; row[x] = s; }
    }
    __syncthreads();

    // 2b. col-prefix: thread x scans column x (lane-consecutive banks, free)
    if (t < W) {
        float s = 0.f;
        for (int y = 0; y < H; ++y) { s += tile[y * TS + t]; tile[y * TS + t] = s; }
    }
    __syncthreads();

    // 3. ROI lookups.  Inclusive integral I[y][x] = sum_{y'<=y, x'<=x}.
    //    rect rows [y0, y0+ys), cols [x0, x0+xs):
    //    S = I[y1][x1] - I[y0-1][x1] - I[y1][x0-1] + I[y0-1][x0-1]
    float* prow = partial + (size_t)p * nrois;
    for (int n = t; n < nrois; n += 256) {
        const int4 r  = ((const int4*)rois)[n];   // ymin,xmin,ymax,xmax
        const int ys  = (r.z - r.x) / KK;
        const int xs  = (r.w - r.y) / KK;
        const int y0  = r.x + j * ys;
        const int x0  = r.y + l * xs;
        const int y1  = y0 + ys - 1;              // <= 94 < 100
        const int x1  = x0 + xs - 1;

        float S = tile[y1 * TS + x1];
        if (x0 > 0)           S -= tile[y1 * TS + (x0 - 1)];
        if (y0 > 0)           S -= tile[(y0 - 1) * TS + x1];
        if (y0 > 0 && x0 > 0) S += tile[(y0 - 1) * TS + (x0 - 1)];

        prow[n] = S;                              // coalesced 4B store
    }
}

// ---------------------------------------------------------------------------
// Stage 2 (fused reduce + softmax): block handles RB=16 ROIs.
// Thread (dn = t%16, cg = t/16) sums channels c = cg, cg+16 over 49 planes
// with 64B-coalesced loads (16 consecutive n per channel-row).  LDS ch[16][21],
// then lanes 0..15 do the per-ROI scale + softmax + store.
// ---------------------------------------------------------------------------
#define RB 16

__global__ __launch_bounds__(256) void reduce_softmax(
    const float* __restrict__ partial,   // [NPLANES][nrois]
    const int*   __restrict__ rois,
    int nrois,
    float*       __restrict__ out)
{
    const int dn = threadIdx.x & (RB - 1);
    const int cg = threadIdx.x / RB;     // 0..15
    const int n  = blockIdx.x * RB + dn;

    __shared__ float ch[RB][C1];

    if (n < nrois) {
        for (int c = cg; c < C1; c += 16) {
            float s = 0.f;
            const float* pc = partial + (size_t)c * nrois + n;
            #pragma unroll
            for (int jl = 0; jl < KK * KK; ++jl) {
                s += pc[(size_t)jl * C1 * nrois];
            }
            ch[dn][c] = s;
        }
    }
    __syncthreads();

    if (threadIdx.x < RB) {
        const int n2 = blockIdx.x * RB + threadIdx.x;
        if (n2 < nrois) {
            const int4 r  = ((const int4*)rois)[n2];
            const int ys  = (r.z - r.x) / KK;
            const int xs  = (r.w - r.y) / KK;
            const float inv = 1.0f / (49.0f * (float)(ys * xs));

            float v[C1];
            float m = -INFINITY;
            #pragma unroll
            for (int c = 0; c < C1; ++c) {
                v[c] = ch[threadIdx.x][c] * inv;
                m = fmaxf(m, v[c]);
            }
            float s = 0.f;
            #pragma unroll
            for (int c = 0; c < C1; ++c) { v[c] = __expf(v[c] - m); s += v[c]; }
            const float rs = 1.0f / s;
            #pragma unroll
            for (int c = 0; c < C1; ++c) out[(size_t)n2 * C1 + c] = v[c] * rs;
        }
    }
}

// ---------------------------------------------------------------------------
// Fallback (ws too small): direct rectangle summation from global.
// ---------------------------------------------------------------------------
__global__ __launch_bounds__(256) void roi_pool_direct(
    const float* __restrict__ src,
    size_t batch_off,
    const int*   __restrict__ rois,
    float*       __restrict__ out)
{
    const int n = blockIdx.x;
    const int t = threadIdx.x;

    __shared__ float chsum[C1];
    if (t < C1) chsum[t] = 0.f;
    __syncthreads();

    const int ymin = rois[4 * n + 0];
    const int xmin = rois[4 * n + 1];
    const int ymax = rois[4 * n + 2];
    const int xmax = rois[4 * n + 3];
    const int ys = (ymax - ymin) / KK;
    const int xs = (xmax - xmin) / KK;

    const float* base = src + batch_off;

    for (int idx = t; idx < NPLANES; idx += blockDim.x) {
        const int c  = idx % C1;
        const int jl = idx / C1;
        const int l  = jl % KK;
        const int j  = jl / KK;
        const int y0 = ymin + j * ys;
        const int x0 = xmin + l * xs;
        const float* plane = base + (size_t)idx * (H * W);
        float s = 0.f;
        for (int y = y0; y < y0 + ys; ++y) {
            const float* row = plane + (size_t)y * W + x0;
            for (int x = 0; x < xs; ++x) s += row[x];
        }
        atomicAdd(&chsum[c], s);
    }
    __syncthreads();

    if (t == 0) {
        const float inv = 1.0f / (49.0f * (float)(ys * xs));
        float m = -INFINITY;
        float v[C1];
        for (int c = 0; c < C1; ++c) { v[c] = chsum[c] * inv; m = fmaxf(m, v[c]); }
        float s = 0.f;
        for (int c = 0; c < C1; ++c) { v[c] = expf(v[c] - m); s += v[c]; }
        const float rs = 1.0f / s;
        for (int c = 0; c < C1; ++c) out[(size_t)n * C1 + c] = v[c] * rs;
    }
}

extern "C" void kernel_launch(void* const* d_in, const int* in_sizes, int n_in,
                              void* d_out, int out_size, void* d_ws, size_t ws_size,
                              hipStream_t stream)
{
    const float* cls  = (const float*)d_in[0];
    const int*   rois = (const int*)d_in[1];
    float*       out  = (float*)d_out;

    const int nrois = in_sizes[1] / 4;                         // 2000
    const size_t plane_elems = (size_t)NPLANES * H * W;        // 10.29 M
    const int B = (int)((size_t)in_sizes[0] / plane_elems);    // 4
    const size_t batch_off = (size_t)(B - 1) * plane_elems;

    const size_t need = (size_t)NPLANES * nrois * sizeof(float);  // ~8.2 MB
    if (ws_size >= need) {
        float* partial = (float*)d_ws;
        plane_partial<<<NPLANES, 256, 0, stream>>>(cls, batch_off, rois, nrois, partial);
        reduce_softmax<<<(nrois + RB - 1) / RB, 256, 0, stream>>>(partial, rois, nrois, out);
    } else {
        roi_pool_direct<<<nrois, 256, 0, stream>>>(cls, batch_off, rois, out);
    }
}

// Round 6
// 216.400 us; speedup vs baseline: 1.4890x; 1.0109x over previous
//
#include <hip/hip_runtime.h>
#include <math.h>

#define KK      7
#define C1      21
#define NPLANES (KK * KK * C1)   // 1029
#define H       100
#define W       100
#define TS      101              // padded LDS row stride: bank stride 5 (coprime 32)
#define NCHUNK  ((H * W) / 4)    // 2500 float4 chunks per plane
#define PREFK   10               // ceil(2500 / 256)

// ---------------------------------------------------------------------------
// Stage 1: one block per PAIR of planes (grid 515 -> all blocks resident in a
// single round at 3 blocks/CU).  Per plane p = (j*7+l)*21 + c:
//  1. stage 100x100 plane in LDS at stride 101 (40.4 KB)
//  2. in-place 2-D inclusive integral (row scan + col scan), conflict-free
//  3. all ROIs: 4 LDS lookups -> partial[p][n]  (plane-major, coalesced store)
// The second plane's tile is prefetched into registers (40 VGPRs/thread)
// while the first plane computes, hiding its HBM latency.
// ---------------------------------------------------------------------------
__global__ __launch_bounds__(256) void plane_partial(
    const float* __restrict__ src,   // full cls_conv_out
    size_t batch_off,                // offset of last batch element (elements)
    const int*  __restrict__ rois,   // [nrois][4] = ymin,xmin,ymax,xmax
    int nrois,
    float* __restrict__ partial)     // [NPLANES][nrois]
{
    const int t  = threadIdx.x;
    const int p0 = blockIdx.x * 2;
    const int p1 = p0 + 1;
    const bool has_p1 = (p1 < NPLANES);

    __shared__ float tile[H * TS];   // 40400 B

    // ---- stage plane 0 (float4 global -> scalar padded LDS) ----
    {
        const float4* p4 = (const float4*)(src + batch_off + (size_t)p0 * (H * W));
        #pragma unroll
        for (int k = 0; k < PREFK; ++k) {
            int i = t + 256 * k;
            if (i < NCHUNK) {
                float4 v = p4[i];
                int g = i * 4;
                int y = g / W, x = g - y * W;        // rows don't split (100%4==0)
                float* d = &tile[y * TS + x];
                d[0] = v.x; d[1] = v.y; d[2] = v.z; d[3] = v.w;
            }
        }
    }
    __syncthreads();

    // ---- issue prefetch of plane 1 into registers (loads stay in flight) ----
    float4 pref[PREFK];
    if (has_p1) {
        const float4* p4 = (const float4*)(src + batch_off + (size_t)p1 * (H * W));
        #pragma unroll
        for (int k = 0; k < PREFK; ++k) {
            int i = t + 256 * k;
            if (i < NCHUNK) pref[k] = p4[i];
        }
    }

    for (int pass = 0; pass < 2; ++pass) {
        const int p = p0 + pass;
        if (p >= NPLANES) break;
        const int jl = p / C1;
        const int l  = jl % KK;
        const int j  = jl / KK;

        if (pass == 1) {
            // overwrite tile with the prefetched plane
            __syncthreads();          // all pass-0 tile reads done
            #pragma unroll
            for (int k = 0; k < PREFK; ++k) {
                int i = t + 256 * k;
                if (i < NCHUNK) {
                    float4 v = pref[k];
                    int g = i * 4;
                    int y = g / W, x = g - y * W;
                    float* d = &tile[y * TS + x];
                    d[0] = v.x; d[1] = v.y; d[2] = v.z; d[3] = v.w;
                }
            }
            __syncthreads();
        }

        // row-prefix: thread y scans row y.  bank(t,x) = (5t + x) & 31:
        // distinct across 32 lanes, 2 lanes/bank across wave64 -> free.
        if (t < H) {
            float s = 0.f;
            float* row = &tile[t * TS];
            for (int x = 0; x < W; ++x) { s += row[x]; row[x] = s; }
        }
        __syncthreads();

        // col-prefix: thread x scans column x (lane-consecutive banks, free)
        if (t < W) {
            float s = 0.f;
            for (int y = 0; y < H; ++y) { s += tile[y * TS + t]; tile[y * TS + t] = s; }
        }
        __syncthreads();

        // ROI lookups.  Inclusive integral I[y][x] = sum_{y'<=y, x'<=x}.
        // rect rows [y0, y0+ys), cols [x0, x0+xs):
        // S = I[y1][x1] - I[y0-1][x1] - I[y1][x0-1] + I[y0-1][x0-1]
        float* prow = partial + (size_t)p * nrois;
        for (int n = t; n < nrois; n += 256) {
            const int4 r  = ((const int4*)rois)[n];   // ymin,xmin,ymax,xmax
            const int ys  = (r.z - r.x) / KK;
            const int xs  = (r.w - r.y) / KK;
            const int y0  = r.x + j * ys;
            const int x0  = r.y + l * xs;
            const int y1  = y0 + ys - 1;              // <= 94 < 100
            const int x1  = x0 + xs - 1;

            float S = tile[y1 * TS + x1];
            if (x0 > 0)           S -= tile[y1 * TS + (x0 - 1)];
            if (y0 > 0)           S -= tile[(y0 - 1) * TS + x1];
            if (y0 > 0 && x0 > 0) S += tile[(y0 - 1) * TS + (x0 - 1)];

            prow[n] = S;                              // coalesced 4B store
        }
    }
}

// ---------------------------------------------------------------------------
// Stage 2 (fused reduce + softmax): block handles RB=16 ROIs.
// Thread (dn = t%16, cg = t/16) sums channels c = cg, cg+16 over 49 planes
// with 64B-coalesced loads (16 consecutive n per channel-row).  LDS ch[16][21],
// then lanes 0..15 do the per-ROI scale + softmax + store.
// ---------------------------------------------------------------------------
#define RB 16

__global__ __launch_bounds__(256) void reduce_softmax(
    const float* __restrict__ partial,   // [NPLANES][nrois]
    const int*   __restrict__ rois,
    int nrois,
    float*       __restrict__ out)
{
    const int dn = threadIdx.x & (RB - 1);
    const int cg = threadIdx.x / RB;     // 0..15
    const int n  = blockIdx.x * RB + dn;

    __shared__ float ch[RB][C1];

    if (n < nrois) {
        for (int c = cg; c < C1; c += 16) {
            float s = 0.f;
            const float* pc = partial + (size_t)c * nrois + n;
            #pragma unroll
            for (int jl = 0; jl < KK * KK; ++jl) {
                s += pc[(size_t)jl * C1 * nrois];
            }
            ch[dn][c] = s;
        }
    }
    __syncthreads();

    if (threadIdx.x < RB) {
        const int n2 = blockIdx.x * RB + threadIdx.x;
        if (n2 < nrois) {
            const int4 r  = ((const int4*)rois)[n2];
            const int ys  = (r.z - r.x) / KK;
            const int xs  = (r.w - r.y) / KK;
            const float inv = 1.0f / (49.0f * (float)(ys * xs));

            float v[C1];
            float m = -INFINITY;
            #pragma unroll
            for (int c = 0; c < C1; ++c) {
                v[c] = ch[threadIdx.x][c] * inv;
                m = fmaxf(m, v[c]);
            }
            float s = 0.f;
            #pragma unroll
            for (int c = 0; c < C1; ++c) { v[c] = __expf(v[c] - m); s += v[c]; }
            const float rs = 1.0f / s;
            #pragma unroll
            for (int c = 0; c < C1; ++c) out[(size_t)n2 * C1 + c] = v[c] * rs;
        }
    }
}

// ---------------------------------------------------------------------------
// Fallback (ws too small): direct rectangle summation from global.
// ---------------------------------------------------------------------------
__global__ __launch_bounds__(256) void roi_pool_direct(
    const float* __restrict__ src,
    size_t batch_off,
    const int*   __restrict__ rois,
    float*       __restrict__ out)
{
    const int n = blockIdx.x;
    const int t = threadIdx.x;

    __shared__ float chsum[C1];
    if (t < C1) chsum[t] = 0.f;
    __syncthreads();

    const int ymin = rois[4 * n + 0];
    const int xmin = rois[4 * n + 1];
    const int ymax = rois[4 * n + 2];
    const int xmax = rois[4 * n + 3];
    const int ys = (ymax - ymin) / KK;
    const int xs = (xmax - xmin) / KK;

    const float* base = src + batch_off;

    for (int idx = t; idx < NPLANES; idx += blockDim.x) {
        const int c  = idx % C1;
        const int jl = idx / C1;
        const int l  = jl % KK;
        const int j  = jl / KK;
        const int y0 = ymin + j * ys;
        const int x0 = xmin + l * xs;
        const float* plane = base + (size_t)idx * (H * W);
        float s = 0.f;
        for (int y = y0; y < y0 + ys; ++y) {
            const float* row = plane + (size_t)y * W + x0;
            for (int x = 0; x < xs; ++x) s += row[x];
        }
        atomicAdd(&chsum[c], s);
    }
    __syncthreads();

    if (t == 0) {
        const float inv = 1.0f / (49.0f * (float)(ys * xs));
        float m = -INFINITY;
        float v[C1];
        for (int c = 0; c < C1; ++c) { v[c] = chsum[c] * inv; m = fmaxf(m, v[c]); }
        float s = 0.f;
        for (int c = 0; c < C1; ++c) { v[c] = expf(v[c] - m); s += v[c]; }
        const float rs = 1.0f / s;
        for (int c = 0; c < C1; ++c) out[(size_t)n * C1 + c] = v[c] * rs;
    }
}

extern "C" void kernel_launch(void* const* d_in, const int* in_sizes, int n_in,
                              void* d_out, int out_size, void* d_ws, size_t ws_size,
                              hipStream_t stream)
{
    const float* cls  = (const float*)d_in[0];
    const int*   rois = (const int*)d_in[1];
    float*       out  = (float*)d_out;

    const int nrois = in_sizes[1] / 4;                         // 2000
    const size_t plane_elems = (size_t)NPLANES * H * W;        // 10.29 M
    const int B = (int)((size_t)in_sizes[0] / plane_elems);    // 4
    const size_t batch_off = (size_t)(B - 1) * plane_elems;

    const size_t need = (size_t)NPLANES * nrois * sizeof(float);  // ~8.2 MB
    if (ws_size >= need) {
        float* partial = (float*)d_ws;
        const int nblocks = (NPLANES + 1) / 2;                 // 515
        plane_partial<<<nblocks, 256, 0, stream>>>(cls, batch_off, rois, nrois, partial);
        reduce_softmax<<<(nrois + RB - 1) / RB, 256, 0, stream>>>(partial, rois, nrois, out);
    } else {
        roi_pool_direct<<<nrois, 256, 0, stream>>>(cls, batch_off, rois, out);
    }
}